// Round 2
// baseline (1517.895 us; speedup 1.0000x reference)
//
#include <hip/hip_runtime.h>

// Problem constants (MGDPR): B=2 R=5 N=1024 E=3 L=2, F=D=64
// IN_RET=320 INTER=256 OUT_RET=256 H1=128 H_RET=320 N_CLS=2, 1/GAMMA=0.4
// All inputs/outputs are FP32 (reference is jnp.float32 end-to-end).
#define NB 2
#define NR 5
#define NN_ 1024
#define NE 3
#define NL 2
#define ND 64

// ---- init: skip[b,n,r*64+f] = x[b,r,n,f] ----
__global__ void init_kernel(const float* __restrict__ x, float* __restrict__ skip) {
    int idx = blockIdx.x * 256 + threadIdx.x;      // B*R*N*64 = 655360
    int d = idx & 63;
    int n = (idx >> 6) & 1023;
    int br = idx >> 16;                             // b*5+r
    int b = br / NR, r = br % NR;
    skip[((size_t)b * NN_ + n) * 320 + r * 64 + d] = x[idx];
}

// ---- feats[b,r,n,d] = sum_m (sum_e theta[l,r,e]*T[l,r,e,n,m]) * a[b,r,n,m] * h[b,r,m,d] ----
// block: (n_tile of 32, b*R+r); 256 threads; LDS-tiled over m in chunks of 64
__global__ __launch_bounds__(256) void feats_kernel(
    const float* __restrict__ T, const float* __restrict__ theta,
    const float* __restrict__ a, const float* __restrict__ h,
    float* __restrict__ feats, int l) {
    __shared__ float wt[32][64];
    __shared__ float hs[64][64];
    int b = blockIdx.y / NR, r = blockIdx.y % NR;
    int n0 = blockIdx.x * 32;
    int tid = threadIdx.x;
    int g = tid >> 6, d = tid & 63;
    float acc[8] = {};
    const float* Tb = T + ((size_t)(l * NR + r)) * NE * NN_ * NN_;
    float th0 = theta[(l * NR + r) * NE + 0];
    float th1 = theta[(l * NR + r) * NE + 1];
    float th2 = theta[(l * NR + r) * NE + 2];
    const float* arow = a + (((size_t)b * NR + r) * NN_ + n0) * NN_;
    const float* hb = h + ((size_t)b * NR + r) * NN_ * ND;
    for (int m0 = 0; m0 < NN_; m0 += 64) {
#pragma unroll
        for (int j = 0; j < 8; ++j) {           // 32x64 weight tile
            int e = tid + j * 256;
            int nn = e >> 6, mm = e & 63;
            size_t o = ((size_t)(n0 + nn)) * NN_ + m0 + mm;
            float s = th0 * Tb[o] + th1 * Tb[(size_t)NN_ * NN_ + o]
                    + th2 * Tb[(size_t)2 * NN_ * NN_ + o];
            wt[nn][mm] = s * arow[(size_t)nn * NN_ + m0 + mm];
        }
#pragma unroll
        for (int j = 0; j < 16; ++j) {          // 64x64 h tile
            int e = tid + j * 256;
            int mm = e >> 6, dd = e & 63;
            hs[mm][dd] = hb[(size_t)(m0 + mm) * ND + dd];
        }
        __syncthreads();
#pragma unroll
        for (int mm = 0; mm < 64; ++mm) {
            float hv = hs[mm][d];
#pragma unroll
            for (int i = 0; i < 8; ++i) acc[i] += wt[g + 4 * i][mm] * hv;  // wt read is wave-broadcast
        }
        __syncthreads();
    }
#pragma unroll
    for (int i = 0; i < 8; ++i)
        feats[(((size_t)b * NR + r) * NN_ + n0 + g + 4 * i) * ND + d] = acc[i];
}

// ---- diff = prelu(feats @ fc_w[l,r]^T + fc_b, a0[l]) ; per-row 64x64 ----
__global__ __launch_bounds__(256) void fc_kernel(
    const float* __restrict__ feats, const float* __restrict__ fc_w,
    const float* __restrict__ fc_b, const float* __restrict__ a0,
    float* __restrict__ diff, int l) {
    __shared__ float frow[4][64];
    int tid = threadIdx.x;
    int sub = tid >> 6, o = tid & 63;
    size_t base = (size_t)blockIdx.x * 4;       // flat row into [B*R*N]
    int br = (int)(base >> 10);
    int r = br % NR;
    size_t row = base + sub;
    frow[sub][o] = feats[row * ND + o];
    __syncthreads();
    const float* w = fc_w + ((size_t)(l * NR + r) * ND) * ND;
    float acc = fc_b[(l * NR + r) * ND + o];
#pragma unroll 8
    for (int dd = 0; dd < ND; ++dd) acc += frow[sub][dd] * w[o * ND + dd];
    float al = a0[l];
    diff[row * ND + o] = (acc >= 0.f) ? acc : al * acc;
}

// ---- u[b,s,n,o] = prelu(sum_r conv_w[l,s,r]*diff[b,r,n,o] + conv_b[l,s], a1[l]) ----
__global__ void conv_kernel(const float* __restrict__ diff,
                            const float* __restrict__ cw,
                            const float* __restrict__ cb,
                            const float* __restrict__ a1,
                            float* __restrict__ u, int l) {
    int idx = blockIdx.x * 256 + threadIdx.x;   // B*R*N*64
    int no = idx & (NN_ * ND - 1);
    int bs = idx >> 16;
    int s = bs % NR, b = bs / NR;
    const float* dbase = diff + (size_t)b * NR * NN_ * ND + no;
    float acc = cb[l * NR + s];
#pragma unroll
    for (int r = 0; r < NR; ++r)
        acc += cw[(l * NR + s) * NR + r] * dbase[(size_t)r * NN_ * ND];
    float al = a1[l];
    u[idx] = (acc >= 0.f) ? acc : al * acc;
}

// ---- generic tiled GEMM: C[m,n] = epi(sum_k A[m,k]*W(n,k)) ----
// w_nn==0: W is [Nw,K] (NT).  w_nn==1: W is [K,Nw] (NN).  All fp32.
// epi: +bias ; tri: val = (m>n)?0.4*val:0 ; prelu with alpha ptr.
__global__ __launch_bounds__(256) void gemm_kernel(
    const float* __restrict__ A, int lda, int M, int K,
    const float* __restrict__ W, int w_nn,
    const float* __restrict__ bias, const float* __restrict__ alpha,
    int tri, float* __restrict__ C, int ldc, int Nw) {
    __shared__ float As[64][33];
    __shared__ float Ws[64][33];
    int tid = threadIdx.x;
    int n0 = blockIdx.x * 64;
    int m0 = blockIdx.y * 64;
    int tx = tid & 15, ty = tid >> 4;
    float acc[4][4] = {};
    for (int k0 = 0; k0 < K; k0 += 32) {
#pragma unroll
        for (int j = 0; j < 8; ++j) {
            int e = tid + j * 256;
            int row = e >> 5, col = e & 31;
            As[row][col] = A[(size_t)(m0 + row) * lda + k0 + col];
        }
        if (!w_nn) {
#pragma unroll
            for (int j = 0; j < 8; ++j) {
                int e = tid + j * 256;
                int row = e >> 5, col = e & 31;
                Ws[row][col] = W[(size_t)(n0 + row) * K + k0 + col];
            }
        } else {
#pragma unroll
            for (int j = 0; j < 8; ++j) {
                int e = tid + j * 256;
                int nn = e & 63, kk = e >> 6;
                Ws[nn][kk] = W[(size_t)(k0 + kk) * Nw + n0 + nn];
            }
        }
        __syncthreads();
#pragma unroll
        for (int kk = 0; kk < 32; ++kk) {
            float ra[4], rw[4];
#pragma unroll
            for (int i = 0; i < 4; ++i) ra[i] = As[ty * 4 + i][kk];
#pragma unroll
            for (int j = 0; j < 4; ++j) rw[j] = Ws[tx * 4 + j][kk];
#pragma unroll
            for (int i = 0; i < 4; ++i)
#pragma unroll
                for (int j = 0; j < 4; ++j) acc[i][j] += ra[i] * rw[j];
        }
        __syncthreads();
    }
    float al = alpha ? *alpha : 0.f;
#pragma unroll
    for (int i = 0; i < 4; ++i) {
        int m = m0 + ty * 4 + i;
#pragma unroll
        for (int j = 0; j < 4; ++j) {
            int n = n0 + tx * 4 + j;
            float v = acc[i][j];
            if (bias) v += bias[n];
            if (tri) v = (m > n) ? 0.4f * v : 0.f;
            if (alpha) v = (v >= 0.f) ? v : al * v;
            C[(size_t)m * ldc + n] = v;
        }
    }
}

// ---- final: out[m,c] = out1[m,:] @ mlp2_w[c,:] + mlp2_b[c] ----
__global__ void final_kernel(const float* __restrict__ out1,
                             const float* __restrict__ w2,
                             const float* __restrict__ b2,
                             float* __restrict__ out) {
    int idx = blockIdx.x * 256 + threadIdx.x;   // 2048*2
    if (idx >= 2048 * 2) return;
    int m = idx >> 1, c = idx & 1;
    float acc = b2[c];
    const float* row = out1 + (size_t)m * 128;
#pragma unroll 8
    for (int dd = 0; dd < 128; ++dd) acc += row[dd] * w2[c * 128 + dd];
    out[idx] = acc;
}

extern "C" void kernel_launch(void* const* d_in, const int* in_sizes, int n_in,
                              void* d_out, int out_size, void* d_ws, size_t ws_size,
                              hipStream_t stream) {
    auto fp = [&](int i) { return (const float*)d_in[i]; };
    const float *x = fp(0), *a = fp(1), *T = fp(2), *theta = fp(3),
        *fc_w = fp(4), *fc_b = fp(5), *conv_w = fp(6), *conv_b = fp(7),
        *a0 = fp(8), *a1 = fp(9), *qw = fp(10), *qb = fp(11), *kw = fp(12), *kb = fp(13),
        *vw = fp(14), *vb = fp(15), *rw = fp(16), *rb = fp(17), *a_ret = fp(18),
        *l1_w = fp(19), *l1_b = fp(20), *l2_w = fp(21), *l2_b = fp(22),
        *m1w = fp(23), *m1b = fp(24), *m2w = fp(25), *m2b = fp(26), *a_mlp = fp(27);

    float* ws = (float*)d_ws;
    float* u0 = ws;     ws += 655360;     // [B,R,N,64] layer-0 output
    float* u1 = ws;     ws += 655360;     // layer-1 output
    float* skip = ws;   ws += 655360;     // [B,N,320]
    float* feats = ws;  ws += 655360;
    float* diff = ws;   ws += 655360;
    float* scores = ws; ws += 2097152;    // [B,N,N]
    float* q = ws;      ws += 524288;     // [B,N,256]
    float* kk = ws;     ws += 524288;
    float* v = ws;      ws += 524288;
    float* ret = ws;    ws += 524288;
    float* cat = ws;    ws += 786432;     // [B,N,384] = [eta | ts]
    float* out1 = ws;   ws += 262144;     // [B,N,128]  (total ~34.1 MB)

    init_kernel<<<2560, 256, 0, stream>>>(x, skip);
    for (int l = 0; l < NL; ++l) {
        const float* h = (l == 0) ? x : u0;
        float* u = (l == 0) ? u0 : u1;
        feats_kernel<<<dim3(32, 10), 256, 0, stream>>>(T, theta, a, h, feats, l);
        fc_kernel<<<2560, 256, 0, stream>>>(feats, fc_w, fc_b, a0, diff, l);
        conv_kernel<<<2560, 256, 0, stream>>>(diff, conv_w, conv_b, a1, u, l);
        // q,k,v: [2048,320] @ [256,320]^T   (xr = raw reshape of u, contiguous)
        gemm_kernel<<<dim3(4, 32), 256, 0, stream>>>(u, 320, 2048, 320,
            qw + (size_t)l * 256 * 320, 0, qb + l * 256, nullptr, 0, q, 256, 256);
        gemm_kernel<<<dim3(4, 32), 256, 0, stream>>>(u, 320, 2048, 320,
            kw + (size_t)l * 256 * 320, 0, kb + l * 256, nullptr, 0, kk, 256, 256);
        gemm_kernel<<<dim3(4, 32), 256, 0, stream>>>(u, 320, 2048, 320,
            vw + (size_t)l * 256 * 320, 0, vb + l * 256, nullptr, 0, v, 256, 256);
        for (int b = 0; b < NB; ++b) {
            // scores = tri(q @ k^T): [1024,256]@[1024,256]^T -> [1024,1024]
            gemm_kernel<<<dim3(16, 16), 256, 0, stream>>>(q + (size_t)b * 262144, 256, 1024, 256,
                kk + (size_t)b * 262144, 0, nullptr, nullptr, 1,
                scores + (size_t)b * 1048576, 1024, 1024);
            // ret = scores @ v (NN): [1024,1024]@[1024,256]
            gemm_kernel<<<dim3(4, 16), 256, 0, stream>>>(scores + (size_t)b * 1048576, 1024, 1024, 1024,
                v + (size_t)b * 262144, 1, nullptr, nullptr, 0,
                ret + (size_t)b * 262144, 256, 256);
        }
        // eta -> cat[:, 0:256] (prelu a_ret)
        gemm_kernel<<<dim3(4, 32), 256, 0, stream>>>(ret, 256, 2048, 256,
            rw + (size_t)l * 256 * 256, 0, rb + l * 256, a_ret + l, 0, cat, 384, 256);
        // ts -> cat[:, 256:384]
        gemm_kernel<<<dim3(2, 32), 256, 0, stream>>>(skip, 320, 2048, 320,
            l1_w + (size_t)l * 128 * 320, 0, l1_b + l * 128, nullptr, 0, cat + 256, 384, 128);
        // skip = cat @ l2_w^T + l2_b
        gemm_kernel<<<dim3(5, 32), 256, 0, stream>>>(cat, 384, 2048, 384,
            l2_w + (size_t)l * 320 * 384, 0, l2_b + l * 320, nullptr, 0, skip, 320, 320);
    }
    // out1 = prelu(skip @ mlp1_w^T + mlp1_b, a_mlp)
    gemm_kernel<<<dim3(2, 32), 256, 0, stream>>>(skip, 320, 2048, 320,
        m1w, 0, m1b, a_mlp, 0, out1, 128, 128);
    final_kernel<<<16, 256, 0, stream>>>(out1, m2w, m2b, (float*)d_out);
}

// Round 3
// 742.390 us; speedup vs baseline: 2.0446x; 2.0446x over previous
//
#include <hip/hip_runtime.h>

// MGDPR: B=2 R=5 N=1024 E=3 L=2, F=D=64; IN_RET=320 INTER=256 OUT_RET=256
// H1=128 H_RET=320 N_CLS=2; D_gamma strictly-lower = 1/2.5 = 0.4. All fp32.
#define NB 2
#define NR 5
#define NN_ 1024
#define NL 2
#define ND 64
#define MSPLIT 4

// ---- init: skip[b,n,r*64+f] = x[b,r,n,f] (float4) ----
__global__ void init_kernel(const float* __restrict__ x, float* __restrict__ skip) {
    int idx = blockIdx.x * 256 + threadIdx.x;      // 163840 float4s
    int d4 = idx & 15;
    int n = (idx >> 4) & 1023;
    int br = idx >> 14;
    int b = br / NR, r = br % NR;
    float4 v = ((const float4*)x)[idx];
    *(float4*)(skip + ((size_t)b * NN_ + n) * 320 + r * 64 + d4 * 4) = v;
}

// ---- feats partial: part[mz][b*R+r][n][d] = sum_{m in chunk} (Σe θ·T)·a·h ----
// grid (n_tiles=32, br=10, mz=MSPLIT); 256 threads
__global__ __launch_bounds__(256) void feats_kernel(
    const float* __restrict__ T, const float* __restrict__ theta,
    const float* __restrict__ a, const float* __restrict__ h,
    float* __restrict__ part, int l) {
    __shared__ float wt[32][64];
    __shared__ float hs[64][64];
    int b = blockIdx.y / NR, r = blockIdx.y % NR;
    int n0 = blockIdx.x * 32;
    int mz = blockIdx.z;
    int tid = threadIdx.x;
    int g = tid >> 6, d = tid & 63;
    float acc[8] = {};
    const float* Tb = T + (size_t)(l * NR + r) * 3 * 1048576;
    float th0 = theta[(l * NR + r) * 3 + 0];
    float th1 = theta[(l * NR + r) * 3 + 1];
    float th2 = theta[(l * NR + r) * 3 + 2];
    const float* ab = a + (size_t)(b * NR + r) * 1048576;
    const float* hb = h + (size_t)(b * NR + r) * 65536;
    int mbeg = mz * (NN_ / MSPLIT), mend = mbeg + NN_ / MSPLIT;
    for (int m0 = mbeg; m0 < mend; m0 += 64) {
#pragma unroll
        for (int j = 0; j < 2; ++j) {           // 32x64 weight tile, float4
            int e = tid + j * 256;
            int nn = e >> 4, m4 = e & 15;
            size_t o = (size_t)(n0 + nn) * NN_ + m0 + m4 * 4;
            float4 t0 = *(const float4*)(Tb + o);
            float4 t1 = *(const float4*)(Tb + 1048576 + o);
            float4 t2 = *(const float4*)(Tb + 2097152 + o);
            float4 av = *(const float4*)(ab + o);
            float4 w4;
            w4.x = (th0 * t0.x + th1 * t1.x + th2 * t2.x) * av.x;
            w4.y = (th0 * t0.y + th1 * t1.y + th2 * t2.y) * av.y;
            w4.z = (th0 * t0.z + th1 * t1.z + th2 * t2.z) * av.z;
            w4.w = (th0 * t0.w + th1 * t1.w + th2 * t2.w) * av.w;
            *(float4*)&wt[nn][m4 * 4] = w4;
        }
#pragma unroll
        for (int j = 0; j < 4; ++j) {           // 64x64 h tile, float4
            int e = tid + j * 256;
            int mm = e >> 4, d4 = e & 15;
            *(float4*)&hs[mm][d4 * 4] = *(const float4*)(hb + (size_t)(m0 + mm) * 64 + d4 * 4);
        }
        __syncthreads();
#pragma unroll
        for (int mm = 0; mm < 64; ++mm) {
            float hv = hs[mm][d];
#pragma unroll
            for (int i = 0; i < 8; ++i) acc[i] += wt[g + 4 * i][mm] * hv;  // wt: wave-uniform broadcast
        }
        __syncthreads();
    }
    float* pb = part + ((size_t)mz * 10 + blockIdx.y) * 65536;
#pragma unroll
    for (int i = 0; i < 8; ++i)
        pb[(size_t)(n0 + g + 4 * i) * 64 + d] = acc[i];
}

// ---- feats = sum_z part[z] (float4) ----
__global__ void feats_reduce(const float* __restrict__ part, float* __restrict__ feats) {
    int idx = blockIdx.x * 256 + threadIdx.x;   // 163840 float4
    float4 s = ((const float4*)part)[idx];
#pragma unroll
    for (int z = 1; z < MSPLIT; ++z) {
        float4 p = ((const float4*)part)[(size_t)z * 163840 + idx];
        s.x += p.x; s.y += p.y; s.z += p.z; s.w += p.w;
    }
    ((float4*)feats)[idx] = s;
}

// ---- u[b,s,:,:] = prelu(sum_r cw[l,s,r]*diff[b,r,:,:] + cb, a1) (float4) ----
__global__ void conv_kernel(const float* __restrict__ diff,
                            const float* __restrict__ cw, const float* __restrict__ cb,
                            const float* __restrict__ a1, float* __restrict__ u, int l) {
    int idx = blockIdx.x * 256 + threadIdx.x;   // 163840 float4
    int no4 = idx & 16383;                      // 65536/4 per (b,s)
    int bs = idx >> 14;
    int s = bs % NR, b = bs / NR;
    const float* dbase = diff + (size_t)b * NR * 65536;
    float bias = cb[l * NR + s];
    float4 acc = make_float4(bias, bias, bias, bias);
#pragma unroll
    for (int r = 0; r < NR; ++r) {
        float w = cw[(l * NR + s) * NR + r];
        float4 dv = *(const float4*)(dbase + (size_t)r * 65536 + no4 * 4);
        acc.x += w * dv.x; acc.y += w * dv.y; acc.z += w * dv.z; acc.w += w * dv.w;
    }
    float al = a1[l];
    acc.x = acc.x >= 0.f ? acc.x : al * acc.x;
    acc.y = acc.y >= 0.f ? acc.y : al * acc.y;
    acc.z = acc.z >= 0.f ? acc.z : al * acc.z;
    acc.w = acc.w >= 0.f ? acc.w : al * acc.w;
    *(float4*)(u + (size_t)bs * 65536 + no4 * 4) = acc;
}

// ---- batched tiled GEMM: C[m,n] = epi(sum_k A[m,k]*W(n,k)) ----
struct BEnt { const float* A; const float* W; const float* bias; float* C; };
struct BArg { BEnt e[10]; };

// w_nn==0: W[Nw][K] (NT). w_nn==1: W[K][Nw] (NN). 64x64 tile, k-major LDS.
// tri: C = (m>n)?0.4*v:0, tiles fully above diag skipped (never read downstream).
// trik: clamp K to m0+64 (A is strictly-lower-triangular scores).
__global__ __launch_bounds__(256) void gemm_kernel(
    BArg bp, int lda, int K, int w_nn,
    const float* __restrict__ alpha, int tri, int trik, int ldc, int Nw) {
    BEnt E = bp.e[blockIdx.z];
    int m0 = blockIdx.y * 64, n0 = blockIdx.x * 64;
    if (tri && (m0 + 63 <= n0)) return;
    int kend = trik ? min(K, m0 + 64) : K;
    __shared__ float As[32][68];
    __shared__ float Ws[32][68];
    int tid = threadIdx.x;
    int tx = tid & 15, ty = tid >> 4;
    float acc[4][4] = {};
    for (int k0 = 0; k0 < kend; k0 += 32) {
#pragma unroll
        for (int j = 0; j < 2; ++j) {           // A: 64 rows x 32 k, f4 along k -> k-major
            int e = tid + j * 256;
            int row = e >> 3, c4 = e & 7;
            float4 va = *(const float4*)(E.A + (size_t)(m0 + row) * lda + k0 + c4 * 4);
            As[c4 * 4 + 0][row] = va.x; As[c4 * 4 + 1][row] = va.y;
            As[c4 * 4 + 2][row] = va.z; As[c4 * 4 + 3][row] = va.w;
        }
        if (!w_nn) {
#pragma unroll
            for (int j = 0; j < 2; ++j) {
                int e = tid + j * 256;
                int row = e >> 3, c4 = e & 7;
                float4 vw = *(const float4*)(E.W + (size_t)(n0 + row) * K + k0 + c4 * 4);
                Ws[c4 * 4 + 0][row] = vw.x; Ws[c4 * 4 + 1][row] = vw.y;
                Ws[c4 * 4 + 2][row] = vw.z; Ws[c4 * 4 + 3][row] = vw.w;
            }
        } else {
#pragma unroll
            for (int j = 0; j < 2; ++j) {
                int e = tid + j * 256;
                int kk = e >> 4, n4 = e & 15;
                *(float4*)&Ws[kk][n4 * 4] =
                    *(const float4*)(E.W + (size_t)(k0 + kk) * Nw + n0 + n4 * 4);
            }
        }
        __syncthreads();
#pragma unroll
        for (int kk = 0; kk < 32; ++kk) {
            float4 ra4 = *(const float4*)&As[kk][ty * 4];
            float4 rw4 = *(const float4*)&Ws[kk][tx * 4];
            float ar[4] = {ra4.x, ra4.y, ra4.z, ra4.w};
            float wr[4] = {rw4.x, rw4.y, rw4.z, rw4.w};
#pragma unroll
            for (int i = 0; i < 4; ++i)
#pragma unroll
                for (int j = 0; j < 4; ++j) acc[i][j] += ar[i] * wr[j];
        }
        __syncthreads();
    }
    float al = alpha ? *alpha : 0.f;
#pragma unroll
    for (int i = 0; i < 4; ++i) {
        int m = m0 + ty * 4 + i;
        float4 o;
        float* op = &o.x;
#pragma unroll
        for (int j = 0; j < 4; ++j) {
            int n = n0 + tx * 4 + j;
            float v = acc[i][j];
            if (E.bias) v += E.bias[n];
            if (tri) v = (m > n) ? 0.4f * v : 0.f;
            if (alpha) v = (v >= 0.f) ? v : al * v;
            op[j] = v;
        }
        *(float4*)(E.C + (size_t)m * ldc + n0 + tx * 4) = o;
    }
}

// ---- final: out[m,c] = out1[m,:] @ mlp2_w[c,:] + mlp2_b[c] ----
__global__ void final_kernel(const float* __restrict__ out1,
                             const float* __restrict__ w2, const float* __restrict__ b2,
                             float* __restrict__ out) {
    int idx = blockIdx.x * 256 + threadIdx.x;   // 4096
    if (idx >= 2048 * 2) return;
    int m = idx >> 1, c = idx & 1;
    float acc = b2[c];
    const float* row = out1 + (size_t)m * 128;
#pragma unroll 8
    for (int dd = 0; dd < 128; ++dd) acc += row[dd] * w2[c * 128 + dd];
    out[idx] = acc;
}

extern "C" void kernel_launch(void* const* d_in, const int* in_sizes, int n_in,
                              void* d_out, int out_size, void* d_ws, size_t ws_size,
                              hipStream_t stream) {
    auto fp = [&](int i) { return (const float*)d_in[i]; };
    const float *x = fp(0), *a = fp(1), *T = fp(2), *theta = fp(3),
        *fc_w = fp(4), *fc_b = fp(5), *conv_w = fp(6), *conv_b = fp(7),
        *a0 = fp(8), *a1 = fp(9), *qw = fp(10), *qb = fp(11), *kw = fp(12), *kb = fp(13),
        *vw = fp(14), *vb = fp(15), *rw = fp(16), *rb = fp(17), *a_ret = fp(18),
        *l1_w = fp(19), *l1_b = fp(20), *l2_w = fp(21), *l2_b = fp(22),
        *m1w = fp(23), *m1b = fp(24), *m2w = fp(25), *m2b = fp(26), *a_mlp = fp(27);

    float* ws = (float*)d_ws;
    float* part = ws;   ws += MSPLIT * 655360;  // feats partials; dead after reduce
    float* scores = part;                        // alias: scores [B,N,N] = 8.4MB < part 10.5MB
    ws += (2097152 > MSPLIT * 655360 ? 2097152 - MSPLIT * 655360 : 0);
    float* u0 = ws;     ws += 655360;
    float* u1 = ws;     ws += 655360;
    float* skip = ws;   ws += 655360;
    float* feats = ws;  ws += 655360;
    float* diff = ws;   ws += 655360;
    float* q = ws;      ws += 524288;
    float* kk = ws;     ws += 524288;
    float* v = ws;      ws += 524288;
    float* ret = ws;    ws += 524288;
    float* cat = ws;    ws += 786432;           // [B,N,384] = [eta | ts]
    float* out1 = ws;   ws += 262144;           // total ~36 MB

    auto B1 = [](const float* A, const float* W, const float* bias, float* C) {
        BArg g; for (int i = 0; i < 10; ++i) g.e[i] = BEnt{A, W, bias, C}; return g;
    };

    init_kernel<<<640, 256, 0, stream>>>(x, skip);
    for (int l = 0; l < NL; ++l) {
        const float* h = (l == 0) ? x : u0;
        float* u = (l == 0) ? u0 : u1;
        feats_kernel<<<dim3(32, 10, MSPLIT), 256, 0, stream>>>(T, theta, a, h, part, l);
        feats_reduce<<<640, 256, 0, stream>>>(part, feats);
        {   // fc: per (b,r) 1024x64 @ 64x64^T, batched z=10
            BArg g;
            for (int z = 0; z < 10; ++z) {
                int r = z % NR;
                g.e[z] = BEnt{feats + (size_t)z * 65536, fc_w + (size_t)(l * NR + r) * 4096,
                              fc_b + (l * NR + r) * 64, diff + (size_t)z * 65536};
            }
            gemm_kernel<<<dim3(1, 16, 10), 256, 0, stream>>>(g, 64, 64, 0, a0 + l, 0, 0, 64, 64);
        }
        conv_kernel<<<640, 256, 0, stream>>>(diff, conv_w, conv_b, a1, u, l);
        {   // qkv batched z=3: [2048,320] @ [256,320]^T
            BArg g = B1(u, qw + (size_t)l * 81920, qb + l * 256, q);
            g.e[1] = BEnt{u, kw + (size_t)l * 81920, kb + l * 256, kk};
            g.e[2] = BEnt{u, vw + (size_t)l * 81920, vb + l * 256, v};
            gemm_kernel<<<dim3(4, 32, 3), 256, 0, stream>>>(g, 320, 320, 0, nullptr, 0, 0, 256, 256);
        }
        {   // scores = tri(q@k^T), batched over b; upper tiles skipped
            BArg g = B1(q, kk, nullptr, scores);
            g.e[1] = BEnt{q + 262144, kk + 262144, nullptr, scores + 1048576};
            gemm_kernel<<<dim3(16, 16, 2), 256, 0, stream>>>(g, 256, 256, 0, nullptr, 1, 0, 1024, 1024);
        }
        {   // ret = scores @ v (NN), K clamped to m0+64
            BArg g = B1(scores, v, nullptr, ret);
            g.e[1] = BEnt{scores + 1048576, v + 262144, nullptr, ret + 262144};
            gemm_kernel<<<dim3(4, 16, 2), 256, 0, stream>>>(g, 1024, 1024, 1, nullptr, 0, 1, 256, 256);
        }
        {   // eta -> cat[:,0:256], prelu(a_ret)
            BArg g = B1(ret, rw + (size_t)l * 65536, rb + l * 256, cat);
            gemm_kernel<<<dim3(4, 32, 1), 256, 0, stream>>>(g, 256, 256, 0, a_ret + l, 0, 0, 384, 256);
        }
        {   // ts -> cat[:,256:384]
            BArg g = B1(skip, l1_w + (size_t)l * 40960, l1_b + l * 128, cat + 256);
            gemm_kernel<<<dim3(2, 32, 1), 256, 0, stream>>>(g, 320, 320, 0, nullptr, 0, 0, 384, 128);
        }
        {   // skip = cat @ l2_w^T + l2_b
            BArg g = B1(cat, l2_w + (size_t)l * 122880, l2_b + l * 320, skip);
            gemm_kernel<<<dim3(5, 32, 1), 256, 0, stream>>>(g, 384, 384, 0, nullptr, 0, 0, 320, 320);
        }
    }
    {   // out1 = prelu(skip @ mlp1_w^T + mlp1_b, a_mlp)
        BArg g = B1(skip, m1w, m1b, out1);
        gemm_kernel<<<dim3(2, 32, 1), 256, 0, stream>>>(g, 320, 320, 0, a_mlp, 0, 0, 128, 128);
    }
    final_kernel<<<16, 256, 0, stream>>>(out1, m2w, m2b, (float*)d_out);
}

// Round 4
// 592.783 us; speedup vs baseline: 2.5606x; 1.2524x over previous
//
#include <hip/hip_runtime.h>

// MGDPR: B=2 R=5 N=1024 E=3 L=2, D=64; IN_RET=320 INTER=256 OUT_RET=256
// H1=128 H_RET=320 N_CLS=2; D_gamma strictly-lower = 0.4. All fp32.
#define NB 2
#define NR 5
#define NN_ 1024
#define NL 2
#define MSPLIT 4

// ---- init: skip[b,n,r*64+f] = x[b,r,n,f] (float4) ----
__global__ void init_kernel(const float* __restrict__ x, float* __restrict__ skip) {
    int idx = blockIdx.x * 256 + threadIdx.x;      // 163840 float4s
    int d4 = idx & 15;
    int n = (idx >> 4) & 1023;
    int br = idx >> 14;
    int b = br / NR, r = br % NR;
    float4 v = ((const float4*)x)[idx];
    *(float4*)(skip + ((size_t)b * NN_ + n) * 320 + r * 64 + d4 * 4) = v;
}

// ---- feats partial: part[mz][br][n][d] = sum_{m chunk} (Σe θ·T)·a·h ----
// 64n x 64d tile per block, 4x4 register blocking, k(=m)-major LDS, prefetch.
__global__ __launch_bounds__(256) void feats_kernel(
    const float* __restrict__ T, const float* __restrict__ theta,
    const float* __restrict__ a, const float* __restrict__ h,
    float* __restrict__ part, int l) {
    __shared__ float As[32][68];   // wt k-major: As[m][n]
    __shared__ float Ws[32][68];   // hs: Ws[m][d]
    int br = blockIdx.y;
    int b = br / NR, r = br % NR;
    int n0 = blockIdx.x * 64;
    int mz = blockIdx.z;
    int tid = threadIdx.x;
    int tx = tid & 15, ty = tid >> 4;
    const float* Tb = T + (size_t)(l * NR + r) * 3145728;
    float th0 = theta[(l * NR + r) * 3 + 0];
    float th1 = theta[(l * NR + r) * 3 + 1];
    float th2 = theta[(l * NR + r) * 3 + 2];
    const float* ab = a + (size_t)(b * NR + r) * 1048576;
    const float* hb = h + (size_t)(b * NR + r) * 65536;
    int mbeg = mz * (NN_ / MSPLIT), mend = mbeg + NN_ / MSPLIT;
    int c4 = tid & 7, nrow = tid >> 3;      // wt staging: (m-float4, n); +256 -> nrow+32
    int d4 = tid & 15, mrow = tid >> 4;     // hs staging: (d-float4, m); +256 -> mrow+16
    float4 pT0[2], pT1[2], pT2[2], pA[2], pH[2];
    auto LOAD = [&](int k0) {
#pragma unroll
        for (int j = 0; j < 2; ++j) {
            size_t o = (size_t)(n0 + nrow + j * 32) * 1024 + k0 + c4 * 4;
            pT0[j] = *(const float4*)(Tb + o);
            pT1[j] = *(const float4*)(Tb + 1048576 + o);
            pT2[j] = *(const float4*)(Tb + 2097152 + o);
            pA[j]  = *(const float4*)(ab + o);
        }
#pragma unroll
        for (int j = 0; j < 2; ++j)
            pH[j] = *(const float4*)(hb + (size_t)(k0 + mrow + j * 16) * 64 + d4 * 4);
    };
    float acc[4][4] = {};
    LOAD(mbeg);
    for (int k0 = mbeg; k0 < mend; k0 += 32) {
        float4 w4[2];
#pragma unroll
        for (int j = 0; j < 2; ++j) {
            w4[j].x = (th0 * pT0[j].x + th1 * pT1[j].x + th2 * pT2[j].x) * pA[j].x;
            w4[j].y = (th0 * pT0[j].y + th1 * pT1[j].y + th2 * pT2[j].y) * pA[j].y;
            w4[j].z = (th0 * pT0[j].z + th1 * pT1[j].z + th2 * pT2[j].z) * pA[j].z;
            w4[j].w = (th0 * pT0[j].w + th1 * pT1[j].w + th2 * pT2[j].w) * pA[j].w;
        }
        __syncthreads();
#pragma unroll
        for (int j = 0; j < 2; ++j) {
            int n = nrow + j * 32;
            As[c4 * 4 + 0][n] = w4[j].x; As[c4 * 4 + 1][n] = w4[j].y;
            As[c4 * 4 + 2][n] = w4[j].z; As[c4 * 4 + 3][n] = w4[j].w;
        }
#pragma unroll
        for (int j = 0; j < 2; ++j)
            *(float4*)&Ws[mrow + j * 16][d4 * 4] = pH[j];
        if (k0 + 32 < mend) LOAD(k0 + 32);
        __syncthreads();
#pragma unroll
        for (int kk = 0; kk < 32; ++kk) {
            float4 ra = *(const float4*)&As[kk][ty * 4];
            float4 rw = *(const float4*)&Ws[kk][tx * 4];
            float ar[4] = {ra.x, ra.y, ra.z, ra.w};
            float wr[4] = {rw.x, rw.y, rw.z, rw.w};
#pragma unroll
            for (int i = 0; i < 4; ++i)
#pragma unroll
                for (int j = 0; j < 4; ++j) acc[i][j] += ar[i] * wr[j];
        }
    }
    float* pb = part + ((size_t)mz * 10 + br) * 65536;
#pragma unroll
    for (int i = 0; i < 4; ++i) {
        float4 o4 = make_float4(acc[i][0], acc[i][1], acc[i][2], acc[i][3]);
        *(float4*)(pb + (size_t)(n0 + ty * 4 + i) * 64 + tx * 4) = o4;
    }
}

// ---- fused: feats = Σz part[z]; diff = prelu(feats @ fc_w[l,r]^T + fc_b, a0) ----
__global__ __launch_bounds__(256) void reduce_fc_kernel(
    const float* __restrict__ part, const float* __restrict__ fc_w,
    const float* __restrict__ fc_b, const float* __restrict__ a0,
    float* __restrict__ diff, int l) {
    __shared__ float F[64][68];    // F[d][n]
    __shared__ float Wl[64][68];   // Wl[d][o]
    int br = blockIdx.y;
    int r = br % NR;
    int n0 = blockIdx.x * 64;
    int tid = threadIdx.x;
    int lane = tid & 63, g = tid >> 6;
#pragma unroll
    for (int j = 0; j < 4; ++j) {
        int d4 = g + j * 4;
        size_t off = (size_t)br * 65536 + (size_t)(n0 + lane) * 64 + d4 * 4;
        float4 s = *(const float4*)(part + off);
#pragma unroll
        for (int z = 1; z < MSPLIT; ++z) {
            float4 p = *(const float4*)(part + (size_t)z * 655360 + off);
            s.x += p.x; s.y += p.y; s.z += p.z; s.w += p.w;
        }
        F[d4 * 4 + 0][lane] = s.x; F[d4 * 4 + 1][lane] = s.y;
        F[d4 * 4 + 2][lane] = s.z; F[d4 * 4 + 3][lane] = s.w;
    }
    const float* w = fc_w + (size_t)(l * NR + r) * 4096;
#pragma unroll
    for (int j = 0; j < 4; ++j) {
        int d4 = g + j * 4;
        float4 wv = *(const float4*)(w + (size_t)lane * 64 + d4 * 4);
        Wl[d4 * 4 + 0][lane] = wv.x; Wl[d4 * 4 + 1][lane] = wv.y;
        Wl[d4 * 4 + 2][lane] = wv.z; Wl[d4 * 4 + 3][lane] = wv.w;
    }
    __syncthreads();
    int tx = tid & 15, ty = tid >> 4;
    float acc[4][4] = {};
#pragma unroll
    for (int kk = 0; kk < 64; ++kk) {
        float4 ra = *(const float4*)&F[kk][ty * 4];
        float4 rw = *(const float4*)&Wl[kk][tx * 4];
        float ar[4] = {ra.x, ra.y, ra.z, ra.w};
        float wr[4] = {rw.x, rw.y, rw.z, rw.w};
#pragma unroll
        for (int i = 0; i < 4; ++i)
#pragma unroll
            for (int j = 0; j < 4; ++j) acc[i][j] += ar[i] * wr[j];
    }
    float al = a0[l];
    const float* bia = fc_b + (l * NR + r) * 64;
#pragma unroll
    for (int i = 0; i < 4; ++i) {
        float4 o4;
        float* op = &o4.x;
#pragma unroll
        for (int j = 0; j < 4; ++j) {
            float v = acc[i][j] + bia[tx * 4 + j];
            op[j] = (v >= 0.f) ? v : al * v;
        }
        *(float4*)(diff + (size_t)br * 65536 + (size_t)(n0 + ty * 4 + i) * 64 + tx * 4) = o4;
    }
}

// ---- u[b,s,:,:] = prelu(sum_r cw*diff[b,r] + cb, a1) (float4) ----
__global__ void conv_kernel(const float* __restrict__ diff,
                            const float* __restrict__ cw, const float* __restrict__ cb,
                            const float* __restrict__ a1, float* __restrict__ u, int l) {
    int idx = blockIdx.x * 256 + threadIdx.x;   // 163840 float4
    int no4 = idx & 16383;
    int bs = idx >> 14;
    int s = bs % NR, b = bs / NR;
    const float* dbase = diff + (size_t)b * NR * 65536;
    float bias = cb[l * NR + s];
    float4 acc = make_float4(bias, bias, bias, bias);
#pragma unroll
    for (int r = 0; r < NR; ++r) {
        float w = cw[(l * NR + s) * NR + r];
        float4 dv = *(const float4*)(dbase + (size_t)r * 65536 + no4 * 4);
        acc.x += w * dv.x; acc.y += w * dv.y; acc.z += w * dv.z; acc.w += w * dv.w;
    }
    float al = a1[l];
    acc.x = acc.x >= 0.f ? acc.x : al * acc.x;
    acc.y = acc.y >= 0.f ? acc.y : al * acc.y;
    acc.z = acc.z >= 0.f ? acc.z : al * acc.z;
    acc.w = acc.w >= 0.f ? acc.w : al * acc.w;
    *(float4*)(u + (size_t)bs * 65536 + no4 * 4) = acc;
}

// ---- batched generic GEMM with per-entry params + prefetch ----
struct BEnt {
    const float* A; const float* W; const float* bias; const float* alpha; float* C;
    int lda, K, Nw, ldc, w_nn, tri, trik;
};
struct BArg { BEnt e[4]; };

__global__ __launch_bounds__(256) void gemm_kernel(BArg bp) {
    BEnt E = bp.e[blockIdx.z];
    int m0 = blockIdx.y * 64, n0 = blockIdx.x * 64;
    if (n0 >= E.Nw) return;
    if (E.tri && (m0 + 63 <= n0)) return;
    int K = E.K;
    int kend = E.trik ? min(K, m0 + 64) : K;
    __shared__ float As[32][68];
    __shared__ float Ws[32][68];
    int tid = threadIdx.x;
    int c4 = tid & 7, row = tid >> 3;       // NT staging; +256 -> row+32
    int n4 = tid & 15, krow = tid >> 4;     // NN staging; +256 -> krow+16
    int tx = tid & 15, ty = tid >> 4;
    const float* Ap = E.A; const float* Wp = E.W;
    int lda = E.lda, Nw = E.Nw;
    int wnn = E.w_nn;
    float4 pA[2], pW[2];
    auto LOAD = [&](int k0) {
#pragma unroll
        for (int j = 0; j < 2; ++j)
            pA[j] = *(const float4*)(Ap + (size_t)(m0 + row + j * 32) * lda + k0 + c4 * 4);
        if (!wnn) {
#pragma unroll
            for (int j = 0; j < 2; ++j)
                pW[j] = *(const float4*)(Wp + (size_t)(n0 + row + j * 32) * K + k0 + c4 * 4);
        } else {
#pragma unroll
            for (int j = 0; j < 2; ++j)
                pW[j] = *(const float4*)(Wp + (size_t)(k0 + krow + j * 16) * Nw + n0 + n4 * 4);
        }
    };
    float acc[4][4] = {};
    LOAD(0);
    for (int k0 = 0; k0 < kend; k0 += 32) {
        __syncthreads();
#pragma unroll
        for (int j = 0; j < 2; ++j) {
            int rr = row + j * 32;
            As[c4 * 4 + 0][rr] = pA[j].x; As[c4 * 4 + 1][rr] = pA[j].y;
            As[c4 * 4 + 2][rr] = pA[j].z; As[c4 * 4 + 3][rr] = pA[j].w;
        }
        if (!wnn) {
#pragma unroll
            for (int j = 0; j < 2; ++j) {
                int rr = row + j * 32;
                Ws[c4 * 4 + 0][rr] = pW[j].x; Ws[c4 * 4 + 1][rr] = pW[j].y;
                Ws[c4 * 4 + 2][rr] = pW[j].z; Ws[c4 * 4 + 3][rr] = pW[j].w;
            }
        } else {
#pragma unroll
            for (int j = 0; j < 2; ++j)
                *(float4*)&Ws[krow + j * 16][n4 * 4] = pW[j];
        }
        if (k0 + 32 < kend) LOAD(k0 + 32);
        __syncthreads();
#pragma unroll
        for (int kk = 0; kk < 32; ++kk) {
            float4 ra = *(const float4*)&As[kk][ty * 4];
            float4 rw = *(const float4*)&Ws[kk][tx * 4];
            float ar[4] = {ra.x, ra.y, ra.z, ra.w};
            float wr[4] = {rw.x, rw.y, rw.z, rw.w};
#pragma unroll
            for (int i = 0; i < 4; ++i)
#pragma unroll
                for (int j = 0; j < 4; ++j) acc[i][j] += ar[i] * wr[j];
        }
    }
    float al = E.alpha ? *E.alpha : 0.f;
#pragma unroll
    for (int i = 0; i < 4; ++i) {
        int m = m0 + ty * 4 + i;
        float4 o4;
        float* op = &o4.x;
#pragma unroll
        for (int j = 0; j < 4; ++j) {
            int n = n0 + tx * 4 + j;
            float v = acc[i][j];
            if (E.bias) v += E.bias[n];
            if (E.tri) v = (m > n) ? 0.4f * v : 0.f;
            if (E.alpha) v = (v >= 0.f) ? v : al * v;
            op[j] = v;
        }
        *(float4*)(E.C + (size_t)m * E.ldc + n0 + tx * 4) = o4;
    }
}

// ---- final: out[m,c] = out1[m,:] @ mlp2_w[c,:] + mlp2_b[c] ----
__global__ void final_kernel(const float* __restrict__ out1,
                             const float* __restrict__ w2, const float* __restrict__ b2,
                             float* __restrict__ out) {
    int idx = blockIdx.x * 256 + threadIdx.x;
    if (idx >= 2048 * 2) return;
    int m = idx >> 1, c = idx & 1;
    float acc = b2[c];
    const float* row = out1 + (size_t)m * 128;
#pragma unroll 8
    for (int dd = 0; dd < 128; ++dd) acc += row[dd] * w2[c * 128 + dd];
    out[idx] = acc;
}

extern "C" void kernel_launch(void* const* d_in, const int* in_sizes, int n_in,
                              void* d_out, int out_size, void* d_ws, size_t ws_size,
                              hipStream_t stream) {
    auto fp = [&](int i) { return (const float*)d_in[i]; };
    const float *x = fp(0), *a = fp(1), *T = fp(2), *theta = fp(3),
        *fc_w = fp(4), *fc_b = fp(5), *conv_w = fp(6), *conv_b = fp(7),
        *a0 = fp(8), *a1 = fp(9), *qw = fp(10), *qb = fp(11), *kw = fp(12), *kb = fp(13),
        *vw = fp(14), *vb = fp(15), *rw = fp(16), *rb = fp(17), *a_ret = fp(18),
        *l1_w = fp(19), *l1_b = fp(20), *l2_w = fp(21), *l2_b = fp(22),
        *m1w = fp(23), *m1b = fp(24), *m2w = fp(25), *m2b = fp(26), *a_mlp = fp(27);

    float* ws = (float*)d_ws;
    float* part = ws;   ws += MSPLIT * 655360;  // 10.5 MB; dead after reduce_fc
    float* scores = part;                        // alias: [B,N,N] 8.4 MB <= part
    float* u0 = ws;     ws += 655360;
    float* u1 = ws;     ws += 655360;
    float* skip = ws;   ws += 655360;
    float* diff = ws;   ws += 655360;
    float* q = ws;      ws += 524288;
    float* kk = ws;     ws += 524288;
    float* v = ws;      ws += 524288;
    float* ret = ws;    ws += 524288;
    float* cat = ws;    ws += 786432;           // [B,N,384] = [eta | ts]
    float* out1 = ws;   ws += 262144;           // total ~33.5 MB

    init_kernel<<<640, 256, 0, stream>>>(x, skip);
    for (int l = 0; l < NL; ++l) {
        const float* h = (l == 0) ? x : u0;
        float* u = (l == 0) ? u0 : u1;
        feats_kernel<<<dim3(16, 10, MSPLIT), 256, 0, stream>>>(T, theta, a, h, part, l);
        reduce_fc_kernel<<<dim3(16, 10), 256, 0, stream>>>(part, fc_w, fc_b, a0, diff, l);
        conv_kernel<<<640, 256, 0, stream>>>(diff, conv_w, conv_b, a1, u, l);
        {   // qkv + ts fused (all depend only on u / skip), z=4
            BArg g;
            g.e[0] = {u, qw + (size_t)l * 81920, qb + l * 256, nullptr, q, 320, 320, 256, 256, 0, 0, 0};
            g.e[1] = {u, kw + (size_t)l * 81920, kb + l * 256, nullptr, kk, 320, 320, 256, 256, 0, 0, 0};
            g.e[2] = {u, vw + (size_t)l * 81920, vb + l * 256, nullptr, v, 320, 320, 256, 256, 0, 0, 0};
            g.e[3] = {skip, l1_w + (size_t)l * 40960, l1_b + l * 128, nullptr, cat + 256, 320, 320, 128, 384, 0, 0, 0};
            gemm_kernel<<<dim3(4, 32, 4), 256, 0, stream>>>(g);
        }
        {   // scores = tri(q @ k^T), per-batch, upper tiles skipped
            BArg g;
            g.e[0] = {q, kk, nullptr, nullptr, scores, 256, 256, 1024, 1024, 0, 1, 0};
            g.e[1] = {q + 262144, kk + 262144, nullptr, nullptr, scores + 1048576, 256, 256, 1024, 1024, 0, 1, 0};
            g.e[2] = g.e[0]; g.e[3] = g.e[0];
            gemm_kernel<<<dim3(16, 16, 2), 256, 0, stream>>>(g);
        }
        {   // ret = scores @ v (NN), K clamped to m0+64
            BArg g;
            g.e[0] = {scores, v, nullptr, nullptr, ret, 1024, 1024, 256, 256, 1, 0, 1};
            g.e[1] = {scores + 1048576, v + 262144, nullptr, nullptr, ret + 262144, 1024, 1024, 256, 256, 1, 0, 1};
            g.e[2] = g.e[0]; g.e[3] = g.e[0];
            gemm_kernel<<<dim3(4, 16, 2), 256, 0, stream>>>(g);
        }
        {   // eta -> cat[:,0:256], prelu(a_ret)
            BArg g;
            g.e[0] = {ret, rw + (size_t)l * 65536, rb + l * 256, a_ret + l, cat, 256, 256, 256, 384, 0, 0, 0};
            g.e[1] = g.e[0]; g.e[2] = g.e[0]; g.e[3] = g.e[0];
            gemm_kernel<<<dim3(4, 32, 1), 256, 0, stream>>>(g);
        }
        {   // skip = cat @ l2_w^T + l2_b
            BArg g;
            g.e[0] = {cat, l2_w + (size_t)l * 122880, l2_b + l * 320, nullptr, skip, 384, 384, 320, 320, 0, 0, 0};
            g.e[1] = g.e[0]; g.e[2] = g.e[0]; g.e[3] = g.e[0];
            gemm_kernel<<<dim3(5, 32, 1), 256, 0, stream>>>(g);
        }
    }
    {   // out1 = prelu(skip @ mlp1_w^T + mlp1_b, a_mlp)
        BArg g;
        g.e[0] = {skip, m1w, m1b, a_mlp, out1, 320, 320, 128, 128, 0, 0, 0};
        g.e[1] = g.e[0]; g.e[2] = g.e[0]; g.e[3] = g.e[0];
        gemm_kernel<<<dim3(2, 32, 1), 256, 0, stream>>>(g);
    }
    final_kernel<<<16, 256, 0, stream>>>(out1, m2w, m2b, (float*)d_out);
}